// Round 9
// baseline (267.912 us; speedup 1.0000x reference)
//
#include <hip/hip_runtime.h>
#include <hip/hip_bf16.h>
#include <math.h>

#define B_ 32
#define L_ 720
#define N_ 512
#define H_ 16
#define D_ 64
#define TOPK_ 8
#define M_ (B_ * L_)          // 23040 rows
#define RPB 8                 // rows per ring block
#define CRCH 16               // center_raw chunks per batch
#define CRL (L_ / CRCH)       // 45
#define PROWS 64              // rows per tail panel

typedef __bf16 bf16x8 __attribute__((ext_vector_type(8)));
typedef float f32x16 __attribute__((ext_vector_type(16)));

// ---------------------------------------------------------------------------
// async 16B global -> LDS (dest = wave-uniform lds base + lane*16)
// ---------------------------------------------------------------------------
__device__ __forceinline__ void async_cp16(const __hip_bfloat16* g, __hip_bfloat16* l) {
    __builtin_amdgcn_global_load_lds(
        (const __attribute__((address_space(1))) void*)g,
        (__attribute__((address_space(3))) void*)l, 16, 0, 0);
}

__device__ __forceinline__ f32x16 fzero16() {
    f32x16 z;
    #pragma unroll
    for (int e = 0; e < 16; ++e) z[e] = 0.f;
    return z;
}

// swizzled full-panel read: element (row, 8-group c8) at row*512 + ((c8^(row&31))*8
__device__ __forceinline__ bf16x8 rsh_ld(const __hip_bfloat16* base, int row, int c8) {
    return *(const bf16x8*)(base + row * 512 + ((c8 ^ (row & 31)) << 3));
}

__device__ __forceinline__ float sigm(float v) { return 1.f / (1.f + expf(-v)); }

// ---------------------------------------------------------------------------
// Kernel 0: prep = Wg/Wf transpose -> bf16 FRAGMENT-MAJOR (pk), + qk tables.
// pk layout (R7-verified): entry [cblk=n>>5][ks32=k>>4][lane=(n&31)+32*((k>>3)&1)][k&7]
// blocks 0..511: col n of Wg/Wf. blocks 512..527: Q/K.
// ---------------------------------------------------------------------------
__global__ __launch_bounds__(512) void prep_kernel(
    const float* __restrict__ Wg, const float* __restrict__ Wf,
    __hip_bfloat16* __restrict__ WgPk, __hip_bfloat16* __restrict__ WfPk,
    const float* __restrict__ ve,
    const float* __restrict__ Wq, const float* __restrict__ bq,
    const float* __restrict__ Wk, const float* __restrict__ bk,
    float* __restrict__ Qm, float* __restrict__ Km)
{
    const int bx = blockIdx.x;
    if (bx < 512) {
        const int n = bx;
        const int k = threadIdx.x;
        const int cblk = n >> 5;
        const int ks32 = k >> 4;
        const int l    = (n & 31) + 32 * ((k >> 3) & 1);
        const size_t pkidx = (((size_t)cblk * 32 + ks32) * 64 + l) * 8 + (k & 7);
        WgPk[pkidx] = __float2bfloat16(Wg[(size_t)k * N_ + n]);
        WfPk[pkidx] = __float2bfloat16(Wf[(size_t)k * N_ + n]);
    } else {
        const int g = (bx - 512) * 512 + threadIdx.x;   // 0..8191
        const int j = g >> 4, h = g & 15;
        const float* vr = ve + j * H_;
        float q = bq[h], k = bk[h];
        #pragma unroll
        for (int m = 0; m < H_; ++m) {
            const float v = vr[m];
            q += v * Wq[m * H_ + h];
            k += v * Wk[m * H_ + h];
        }
        Qm[g] = q;
        Km[g] = k;
    }
}

// ---------------------------------------------------------------------------
// Kernel 1: top-8 neighbors. One wave per row n; shuffle-only selection.
// ---------------------------------------------------------------------------
__global__ __launch_bounds__(64) void topk_kernel(
    const float* __restrict__ Qm, const float* __restrict__ Km,
    float* __restrict__ w_out, int* __restrict__ idx_out)
{
    const int n = blockIdx.x;
    const int lane = threadIdx.x;

    float4 q0, q1, q2, q3;
    {
        const float4* qr = (const float4*)(Qm + n * H_);
        q0 = qr[0]; q1 = qr[1]; q2 = qr[2]; q3 = qr[3];
    }

    float sv[8]; int si[8];
    #pragma unroll
    for (int c = 0; c < 8; ++c) {
        const int j = c * 64 + lane;
        const float4* kr = (const float4*)(Km + j * H_);
        float4 k0 = kr[0], k1 = kr[1], k2 = kr[2], k3 = kr[3];
        float s = q0.x * k0.x + q0.y * k0.y + q0.z * k0.z + q0.w * k0.w
                + q1.x * k1.x + q1.y * k1.y + q1.z * k1.z + q1.w * k1.w
                + q2.x * k2.x + q2.y * k2.y + q2.z * k2.z + q2.w * k2.w
                + q3.x * k3.x + q3.y * k3.y + q3.z * k3.z + q3.w * k3.w;
        sv[c] = (j == n) ? -1e9f : s;
        si[c] = j;
    }

    float keepv[TOPK_]; int keepi[TOPK_];
    #pragma unroll
    for (int k = 0; k < TOPK_; ++k) {
        float bv = sv[0]; int bi = si[0]; int bslot = 0;
        #pragma unroll
        for (int c = 1; c < 8; ++c)
            if (sv[c] > bv || (sv[c] == bv && si[c] < bi)) { bv = sv[c]; bi = si[c]; bslot = c; }
        float v = bv; int i = bi;
        #pragma unroll
        for (int off = 32; off > 0; off >>= 1) {
            float v2 = __shfl_xor(v, off);
            int   i2 = __shfl_xor(i, off);
            if (v2 > v || (v2 == v && i2 < i)) { v = v2; i = i2; }
        }
        keepv[k] = v; keepi[k] = i;
        if (i == bi) sv[bslot] = -INFINITY;
    }

    if (lane == 0) {
        float vmax = keepv[0];
        float ev[TOPK_], esum = 0.f;
        #pragma unroll
        for (int k = 0; k < TOPK_; k++) { ev[k] = expf(keepv[k] - vmax); esum += ev[k]; }
        float inv = 1.f / esum;
        #pragma unroll
        for (int k = 0; k < TOPK_; k++) {
            w_out[n * TOPK_ + k] = ev[k] * inv;
            idx_out[n * TOPK_ + k] = keepi[k];
        }
    }
}

// ---------------------------------------------------------------------------
// Kernel 2: ring gather -> bf16 A matrix, fused with score s = x·Wscore+b.
// ---------------------------------------------------------------------------
__global__ __launch_bounds__(512) void ring_kernel(
    const float* __restrict__ x, const float* __restrict__ w,
    const int* __restrict__ idx,
    const float* __restrict__ Wscore, const float* __restrict__ bscore,
    __hip_bfloat16* __restrict__ ring, float* __restrict__ s)
{
    __shared__ float xs[RPB][N_];
    __shared__ float wsh[N_ * TOPK_];
    __shared__ int   ish[N_ * TOPK_];
    const int t = threadIdx.x;
    const int row0 = blockIdx.x * RPB;

    for (int i = t; i < N_ * TOPK_; i += 512) { wsh[i] = w[i]; ish[i] = idx[i]; }
    {
        const float4* xg = (const float4*)(x + (size_t)row0 * N_);
        float4* xsf = (float4*)&xs[0][0];
        xsf[t] = xg[t];
        xsf[t + 512] = xg[t + 512];
    }
    __syncthreads();

    {
        const int wv = t >> 6, lane = t & 63;
        float sa = 0.f;
        #pragma unroll
        for (int i = 0; i < 8; ++i) sa += xs[wv][lane + i * 64] * Wscore[lane + i * 64];
        for (int off = 32; off > 0; off >>= 1) sa += __shfl_down(sa, off);
        if (lane == 0) s[row0 + wv] = sa + bscore[0];
    }

    float wr[TOPK_]; int ir[TOPK_];
    #pragma unroll
    for (int k = 0; k < TOPK_; ++k) { wr[k] = wsh[t * TOPK_ + k]; ir[k] = ish[t * TOPK_ + k]; }
    #pragma unroll
    for (int r = 0; r < RPB; ++r) {
        float acc = 0.f;
        #pragma unroll
        for (int k = 0; k < TOPK_; ++k) acc += wr[k] * xs[r][ir[k]];
        ring[(size_t)(row0 + r) * N_ + t] = __float2bfloat16(acc);
    }
}

// ---------------------------------------------------------------------------
// Kernel 3: center_raw with inline softmax. grid B_*CRCH, 512 thr.
// ---------------------------------------------------------------------------
__global__ __launch_bounds__(512) void center_raw_kernel(
    const float* __restrict__ x, const float* __restrict__ s,
    float* __restrict__ craw_p)
{
    const int b = blockIdx.x >> 4;
    const int c = blockIdx.x & 15;
    const int n = threadIdx.x;
    __shared__ float red[8];
    __shared__ float ash[CRL];
    const float* srow = s + (size_t)b * L_;

    float lmax = -1e30f;
    for (int l = n; l < L_; l += 512) lmax = fmaxf(lmax, srow[l]);
    for (int off = 32; off > 0; off >>= 1) lmax = fmaxf(lmax, __shfl_down(lmax, off));
    if ((n & 63) == 0) red[n >> 6] = lmax;
    __syncthreads();
    float gmax = red[0];
    #pragma unroll
    for (int w = 1; w < 8; ++w) gmax = fmaxf(gmax, red[w]);
    __syncthreads();

    float lsum = 0.f;
    for (int l = n; l < L_; l += 512) lsum += expf(srow[l] - gmax);
    for (int off = 32; off > 0; off >>= 1) lsum += __shfl_down(lsum, off);
    if ((n & 63) == 0) red[n >> 6] = lsum;
    __syncthreads();
    float tsum = 0.f;
    #pragma unroll
    for (int w = 0; w < 8; ++w) tsum += red[w];
    const float inv = 1.f / tsum;

    const int l0 = c * CRL;
    if (n < CRL) ash[n] = expf(srow[l0 + n] - gmax) * inv;
    __syncthreads();

    const float* xb = x + ((size_t)b * L_ + l0) * N_;
    float acc = 0.f;
    #pragma unroll 3
    for (int l = 0; l < CRL; l++) acc += ash[l] * xb[(size_t)l * N_ + n];
    craw_p[(size_t)(b * CRCH + c) * N_ + n] = acc;
}

__device__ __forceinline__ float gelu_exact(float v) {
    return 0.5f * v * (1.0f + erff(v * 0.70710678118654752440f));
}

// ---------------------------------------------------------------------------
// Kernel 4: reduce partials + center MLP -> center. grid B_, 512 thr.
// ---------------------------------------------------------------------------
__global__ __launch_bounds__(512) void center_mlp_kernel(
    const float* __restrict__ craw_p,
    const float* __restrict__ Wc1, const float* __restrict__ bc1,
    const float* __restrict__ Wc2, const float* __restrict__ bc2,
    const float* __restrict__ Wcn, const float* __restrict__ bcn,
    float* __restrict__ center)
{
    const int b = blockIdx.x;
    const int t = threadIdx.x;
    const int col = t & 63;
    const int seg = t >> 6;
    __shared__ float cr[N_];
    __shared__ float psum[8][D_];
    __shared__ float h1[D_];
    __shared__ float h2[D_];

    {
        float acc = 0.f;
        #pragma unroll
        for (int c = 0; c < CRCH; ++c) acc += craw_p[(size_t)(b * CRCH + c) * N_ + t];
        cr[t] = acc;
    }
    __syncthreads();
    {
        float p = 0.f;
        #pragma unroll 8
        for (int m = seg * 64; m < seg * 64 + 64; ++m) p += cr[m] * Wc1[m * D_ + col];
        psum[seg][col] = p;
    }
    __syncthreads();
    if (t < D_) {
        float acc = bc1[t];
        #pragma unroll
        for (int s2 = 0; s2 < 8; ++s2) acc += psum[s2][t];
        h1[t] = gelu_exact(acc);
    }
    __syncthreads();
    if (t < D_) {
        float acc = bc2[t];
        #pragma unroll 8
        for (int j = 0; j < D_; j++) acc += h1[j] * Wc2[j * D_ + t];
        h2[t] = gelu_exact(acc);
    }
    __syncthreads();
    {
        float acc = bcn[t];
        #pragma unroll 8
        for (int j = 0; j < D_; j++) acc += h2[j] * Wcn[j * N_ + t];
        center[b * N_ + t] = acc;
    }
}

// ---------------------------------------------------------------------------
// Kernel 5: cg[b,n] = center[b]·Wg[512+.,n] + bg[n]. (parallel form)
// ---------------------------------------------------------------------------
__global__ __launch_bounds__(512) void cg_kernel(
    const float* __restrict__ center, const float* __restrict__ Wg,
    const float* __restrict__ bg, float* __restrict__ cg)
{
    const int nc = blockIdx.x;
    const int b  = blockIdx.y;
    const int t  = threadIdx.x;
    const int col = nc * 64 + (t & 63);
    const int seg = t >> 6;
    __shared__ float cs[N_];
    __shared__ float psum[8][64];

    cs[t] = center[b * N_ + t];
    __syncthreads();
    {
        float p = 0.f;
        const float* wp = Wg + (size_t)(N_ + seg * 64) * N_ + col;
        #pragma unroll 8
        for (int m = 0; m < 64; ++m) { p += cs[seg * 64 + m] * wp[0]; wp += N_; }
        psum[seg][t & 63] = p;
    }
    __syncthreads();
    if (t < 64) {
        float acc = bg[nc * 64 + t];
        #pragma unroll
        for (int s2 = 0; s2 < 8; ++s2) acc += psum[s2][t];
        cg[b * N_ + nc * 64 + t] = acc;
    }
}

// ---------------------------------------------------------------------------
// Kernel 6: fused tail v3 -- gate GEMM + sigmoid mix + out GEMM + LN.
// One block = 64-row panel x all 512 cols, 512 thr (8 waves).
// vs R8 (PROWS=32): same W loads per iteration (2x1KB frag-major) but FOUR
// MFMAs per pair (d0,d1 row-subtiles) -> 2x compute per load-latency, and
// W L2 traffic halves (360 blocks x 1MB). All R8-verified pieces kept:
// frag-major W direct-global, in-place fused in swizzled Rsh, two-row-group
// epilogue + LN (R4's exact ps[8][2][32] reduce). LDS ~76KB -> 2 blk/CU.
// ---------------------------------------------------------------------------
__global__ __launch_bounds__(512) void tail_kernel(
    const __hip_bfloat16* __restrict__ ring,
    const __hip_bfloat16* __restrict__ WgPk,
    const __hip_bfloat16* __restrict__ WfPk,
    const float* __restrict__ cg,
    const float* __restrict__ center,
    const float* __restrict__ x,
    const float* __restrict__ bfv,
    const float* __restrict__ gamma,
    const float* __restrict__ beta,
    float* __restrict__ out)
{
    __shared__ __attribute__((aligned(16))) __hip_bfloat16 Rsh[PROWS * N_]; // 64 KB
    __shared__ float cgs[2][N_];
    __shared__ float cents[2][N_];
    __shared__ float ps[8][2][32];
    __shared__ float pq[8][2][32];

    const int tid  = threadIdx.x;
    const int lane = tid & 63;
    const int wv8  = tid >> 6;        // 0..7, owns cols [wv8*64, +64)
    const int m32  = lane & 31;
    const int half = lane >> 5;
    const int row0 = blockIdx.x * PROWS;
    const int b0   = row0 / L_;
    const int b1   = (row0 + PROWS - 1) / L_;
    const int rowg0 = row0 + m32;            // row-group 0 sample row
    const int rowg1 = row0 + 32 + m32;       // row-group 1 sample row
    const int bsel0 = (rowg0 / L_ != b0) ? 1 : 0;
    const int bsel1 = (rowg1 / L_ != b0) ? 1 : 0;

    // ---- stage tables + full ring panel (pre-swizzled source, linear dest) --
    for (int i = tid; i < N_; i += 512) {
        cgs[0][i]   = cg[b0 * N_ + i];
        cgs[1][i]   = cg[b1 * N_ + i];
        cents[0][i] = center[b0 * N_ + i];
        cents[1][i] = center[b1 * N_ + i];
    }
    #pragma unroll
    for (int r = 0; r < 8; ++r) {
        const int row = r * 8 + wv8;
        const int c8s = lane ^ (row & 31);
        async_cp16(ring + (size_t)(row0 + row) * N_ + c8s * 8,
                   Rsh + row * 512);
    }
    __syncthreads();   // drains vmcnt: panel + tables ready

    // ---- gate GEMM: barrier-free, W direct frag-major, 4 MFMA / W-pair ----
    f32x16 ga00 = fzero16(), ga01 = fzero16();   // row-group 0, col-sub 0/1
    f32x16 ga10 = fzero16(), ga11 = fzero16();   // row-group 1
    {
        const __hip_bfloat16* wbase = WgPk + ((size_t)(wv8 * 2) * 32 * 64 + lane) * 8;
        #pragma unroll 8
        for (int ks32 = 0; ks32 < 32; ++ks32) {
            const int c8 = ks32 * 2 + half;
            bf16x8 d0 = rsh_ld(Rsh, m32, c8);
            bf16x8 d1 = rsh_ld(Rsh, 32 + m32, c8);
            bf16x8 wa = *(const bf16x8*)(wbase + (size_t)ks32 * 64 * 8);
            bf16x8 wb = *(const bf16x8*)(wbase + (size_t)(32 * 64 + ks32 * 64) * 8);
            ga00 = __builtin_amdgcn_mfma_f32_32x32x16_bf16(wa, d0, ga00, 0, 0, 0);
            ga01 = __builtin_amdgcn_mfma_f32_32x32x16_bf16(wb, d0, ga01, 0, 0, 0);
            ga10 = __builtin_amdgcn_mfma_f32_32x32x16_bf16(wa, d1, ga10, 0, 0, 0);
            ga11 = __builtin_amdgcn_mfma_f32_32x32x16_bf16(wb, d1, ga11, 0, 0, 0);
        }
    }
    __syncthreads();   // all Rsh reads complete before in-place overwrite

    // ---- gate epilogue: sigmoid mix -> fused, in place in Rsh ----
#define GEPI(AC, G, I)                                                         \
    {                                                                          \
        const int ntb = (wv8 * 2 + (I)) * 32;                                  \
        const int lrow = (G) * 32 + m32;                                       \
        const int bsel = (G) ? bsel1 : bsel0;                                  \
        const int rowg = (G) ? rowg1 : rowg0;                                  \
        _Pragma("unroll") for (int q = 0; q < 4; ++q) {                        \
            const int nb = ntb + 8 * q + 4 * half;                             \
            const float4 cgq = *(const float4*)&cgs[bsel][nb];                 \
            const float4 ctq = *(const float4*)&cents[bsel][nb];               \
            __hip_bfloat16* slot = Rsh + lrow * 512 +                          \
                                   (((nb >> 3) ^ m32) << 3) + (nb & 7);        \
            const uint2 rvp = *(const uint2*)slot;                             \
            const float rv0 = __uint_as_float((rvp.x & 0xffffu) << 16);        \
            const float rv1 = __uint_as_float((rvp.x >> 16) << 16);            \
            const float rv2 = __uint_as_float((rvp.y & 0xffffu) << 16);        \
            const float rv3 = __uint_as_float((rvp.y >> 16) << 16);            \
            const float g0 = sigm(AC[4 * q + 0] + cgq.x);                      \
            const float g1 = sigm(AC[4 * q + 1] + cgq.y);                      \
            const float g2 = sigm(AC[4 * q + 2] + cgq.z);                      \
            const float g3 = sigm(AC[4 * q + 3] + cgq.w);                      \
            const float f0 = g0 * rv0 + (1.f - g0) * ctq.x;                    \
            const float f1 = g1 * rv1 + (1.f - g1) * ctq.y;                    \
            const float f2 = g2 * rv2 + (1.f - g2) * ctq.z;                    \
            const float f3 = g3 * rv3 + (1.f - g3) * ctq.w;                    \
            uint2 wpk;                                                         \
            wpk.x = (unsigned)__builtin_bit_cast(unsigned short, __float2bfloat16(f0)) |        \
                    ((unsigned)__builtin_bit_cast(unsigned short, __float2bfloat16(f1)) << 16); \
            wpk.y = (unsigned)__builtin_bit_cast(unsigned short, __float2bfloat16(f2)) |        \
                    ((unsigned)__builtin_bit_cast(unsigned short, __float2bfloat16(f3)) << 16); \
            *(uint2*)slot = wpk;                                               \
        }                                                                      \
    }
    GEPI(ga00, 0, 0) GEPI(ga01, 0, 1) GEPI(ga10, 1, 0) GEPI(ga11, 1, 1)
    __syncthreads();   // fused panel complete

    // ---- out GEMM: barrier-free, W direct frag-major ----
    f32x16 oc00 = fzero16(), oc01 = fzero16();
    f32x16 oc10 = fzero16(), oc11 = fzero16();
    {
        const __hip_bfloat16* wbase = WfPk + ((size_t)(wv8 * 2) * 32 * 64 + lane) * 8;
        #pragma unroll 8
        for (int ks32 = 0; ks32 < 32; ++ks32) {
            const int c8 = ks32 * 2 + half;
            bf16x8 d0 = rsh_ld(Rsh, m32, c8);
            bf16x8 d1 = rsh_ld(Rsh, 32 + m32, c8);
            bf16x8 wa = *(const bf16x8*)(wbase + (size_t)ks32 * 64 * 8);
            bf16x8 wb = *(const bf16x8*)(wbase + (size_t)(32 * 64 + ks32 * 64) * 8);
            oc00 = __builtin_amdgcn_mfma_f32_32x32x16_bf16(wa, d0, oc00, 0, 0, 0);
            oc01 = __builtin_amdgcn_mfma_f32_32x32x16_bf16(wb, d0, oc01, 0, 0, 0);
            oc10 = __builtin_amdgcn_mfma_f32_32x32x16_bf16(wa, d1, oc10, 0, 0, 0);
            oc11 = __builtin_amdgcn_mfma_f32_32x32x16_bf16(wb, d1, oc11, 0, 0, 0);
        }
    }

    // ---- out epilogue: h = acc + bf + x; accumulate LN stats ----
    float ls[2] = {0.f, 0.f};
    float lq[2] = {0.f, 0.f};
#define OEPI2(AC, G, I)                                                        \
    {                                                                          \
        const int ntb = (wv8 * 2 + (I)) * 32;                                  \
        const int rowg = (G) ? rowg1 : rowg0;                                  \
        _Pragma("unroll") for (int q = 0; q < 4; ++q) {                        \
            const int nb = ntb + 8 * q + 4 * half;                             \
            const float4 bq = *(const float4*)(bfv + nb);                      \
            const float4 xq = *(const float4*)(x + (size_t)rowg * N_ + nb);    \
            AC[4 * q + 0] += bq.x + xq.x;                                      \
            AC[4 * q + 1] += bq.y + xq.y;                                      \
            AC[4 * q + 2] += bq.z + xq.z;                                      \
            AC[4 * q + 3] += bq.w + xq.w;                                      \
            ls[G] += AC[4 * q + 0] + AC[4 * q + 1] + AC[4 * q + 2] + AC[4 * q + 3]; \
            lq[G] += AC[4 * q + 0] * AC[4 * q + 0] + AC[4 * q + 1] * AC[4 * q + 1]  \
                   + AC[4 * q + 2] * AC[4 * q + 2] + AC[4 * q + 3] * AC[4 * q + 3]; \
        }                                                                      \
    }
    OEPI2(oc00, 0, 0) OEPI2(oc01, 0, 1) OEPI2(oc10, 1, 0) OEPI2(oc11, 1, 1)

    // ---- LN reduce: halves via shuffle, waves via LDS (R4-verified) ----
    #pragma unroll
    for (int g = 0; g < 2; ++g) {
        ls[g] += __shfl_xor(ls[g], 32);
        lq[g] += __shfl_xor(lq[g], 32);
    }
    if (half == 0) {
        ps[wv8][0][m32] = ls[0]; pq[wv8][0][m32] = lq[0];
        ps[wv8][1][m32] = ls[1]; pq[wv8][1][m32] = lq[1];
    }
    __syncthreads();

    float mu_[2], inv_[2];
    #pragma unroll
    for (int g = 0; g < 2; ++g) {
        float S = 0.f, Q2 = 0.f;
        #pragma unroll
        for (int w = 0; w < 8; ++w) { S += ps[w][g][m32]; Q2 += pq[w][g][m32]; }
        mu_[g]  = S * (1.0f / N_);
        const float var = Q2 * (1.0f / N_) - mu_[g] * mu_[g];
        inv_[g] = rsqrtf(var + 1e-5f);
    }

#define LSTORE2(AC, G, I)                                                      \
    {                                                                          \
        const int ntb = (wv8 * 2 + (I)) * 32;                                  \
        const int rowg = (G) ? rowg1 : rowg0;                                  \
        const float mu = mu_[G], inv = inv_[G];                                \
        _Pragma("unroll") for (int q = 0; q < 4; ++q) {                        \
            const int nb = ntb + 8 * q + 4 * half;                             \
            const float4 g4 = *(const float4*)(gamma + nb);                    \
            const float4 b4 = *(const float4*)(beta + nb);                     \
            float4 o;                                                          \
            o.x = (AC[4 * q + 0] - mu) * inv * g4.x + b4.x;                    \
            o.y = (AC[4 * q + 1] - mu) * inv * g4.y + b4.y;                    \
            o.z = (AC[4 * q + 2] - mu) * inv * g4.z + b4.z;                    \
            o.w = (AC[4 * q + 3] - mu) * inv * g4.w + b4.w;                    \
            *(float4*)(out + (size_t)rowg * N_ + nb) = o;                      \
        }                                                                      \
    }
    LSTORE2(oc00, 0, 0) LSTORE2(oc01, 0, 1) LSTORE2(oc10, 1, 0) LSTORE2(oc11, 1, 1)
}

// ---------------------------------------------------------------------------
extern "C" void kernel_launch(void* const* d_in, const int* in_sizes, int n_in,
                              void* d_out, int out_size, void* d_ws, size_t ws_size,
                              hipStream_t stream) {
    const float* x       = (const float*)d_in[0];
    const float* ve      = (const float*)d_in[1];
    const float* Wq      = (const float*)d_in[2];
    const float* bq      = (const float*)d_in[3];
    const float* Wk      = (const float*)d_in[4];
    const float* bk      = (const float*)d_in[5];
    const float* Wscore  = (const float*)d_in[6];
    const float* bscore  = (const float*)d_in[7];
    const float* Wc1     = (const float*)d_in[8];
    const float* bc1     = (const float*)d_in[9];
    const float* Wc2     = (const float*)d_in[10];
    const float* bc2     = (const float*)d_in[11];
    const float* Wcn     = (const float*)d_in[12];
    const float* bcn     = (const float*)d_in[13];
    const float* Wg      = (const float*)d_in[14];
    const float* bg      = (const float*)d_in[15];
    const float* Wf      = (const float*)d_in[16];
    const float* bf      = (const float*)d_in[17];
    const float* gamma   = (const float*)d_in[18];
    const float* beta    = (const float*)d_in[19];
    float* out = (float*)d_out;

    char* p = (char*)d_ws;
    float* ws_w    = (float*)p; p += N_ * TOPK_ * sizeof(float);
    int*   ws_idx  = (int*)p;   p += N_ * TOPK_ * sizeof(int);
    float* ws_s    = (float*)p; p += B_ * L_ * sizeof(float);
    float* ws_crp  = (float*)p; p += B_ * CRCH * N_ * sizeof(float);
    float* ws_cent = (float*)p; p += B_ * N_ * sizeof(float);
    float* ws_cg   = (float*)p; p += B_ * N_ * sizeof(float);
    float* ws_Q    = (float*)p; p += N_ * H_ * sizeof(float);
    float* ws_K    = (float*)p; p += N_ * H_ * sizeof(float);
    __hip_bfloat16* ws_ring  = (__hip_bfloat16*)p; p += (size_t)M_ * N_ * sizeof(__hip_bfloat16);
    __hip_bfloat16* ws_WgPk  = (__hip_bfloat16*)p; p += (size_t)N_ * N_ * sizeof(__hip_bfloat16);
    __hip_bfloat16* ws_WfPk  = (__hip_bfloat16*)p; p += (size_t)N_ * N_ * sizeof(__hip_bfloat16);

    prep_kernel<<<528, 512, 0, stream>>>(Wg, Wf, ws_WgPk, ws_WfPk,
                                         ve, Wq, bq, Wk, bk, ws_Q, ws_K);
    topk_kernel<<<N_, 64, 0, stream>>>(ws_Q, ws_K, ws_w, ws_idx);
    ring_kernel<<<M_ / RPB, 512, 0, stream>>>(x, ws_w, ws_idx, Wscore, bscore,
                                              ws_ring, ws_s);
    center_raw_kernel<<<B_ * CRCH, 512, 0, stream>>>(x, ws_s, ws_crp);
    center_mlp_kernel<<<B_, 512, 0, stream>>>(ws_crp, Wc1, bc1, Wc2, bc2,
                                              Wcn, bcn, ws_cent);
    cg_kernel<<<dim3(8, B_), 512, 0, stream>>>(ws_cent, Wg, bg, ws_cg);
    tail_kernel<<<M_ / PROWS, 512, 0, stream>>>(ws_ring, ws_WgPk, ws_WfPk,
                                                ws_cg, ws_cent, x, bf,
                                                gamma, beta, out);
}

// Round 10
// 250.092 us; speedup vs baseline: 1.0713x; 1.0713x over previous
//
#include <hip/hip_runtime.h>
#include <hip/hip_bf16.h>
#include <math.h>

#define B_ 32
#define L_ 720
#define N_ 512
#define H_ 16
#define D_ 64
#define TOPK_ 8
#define M_ (B_ * L_)          // 23040 rows
#define RPB 8                 // rows per ring block
#define CRCH 16               // center_raw chunks per batch
#define CRL (L_ / CRCH)       // 45
#define PROWS 32              // rows per tail panel

typedef __bf16 bf16x8 __attribute__((ext_vector_type(8)));
typedef float f32x16 __attribute__((ext_vector_type(16)));

// ---------------------------------------------------------------------------
// async 16B global -> LDS (dest = wave-uniform lds base + lane*16)
// ---------------------------------------------------------------------------
__device__ __forceinline__ void async_cp16(const __hip_bfloat16* g, __hip_bfloat16* l) {
    __builtin_amdgcn_global_load_lds(
        (const __attribute__((address_space(1))) void*)g,
        (__attribute__((address_space(3))) void*)l, 16, 0, 0);
}

__device__ __forceinline__ f32x16 fzero16() {
    f32x16 z;
    #pragma unroll
    for (int e = 0; e < 16; ++e) z[e] = 0.f;
    return z;
}

// swizzled full-panel read: element (row, 8-group c8) at row*512 + (c8^(row&31))*8
__device__ __forceinline__ bf16x8 rsh_ld(const __hip_bfloat16* base, int row, int c8) {
    return *(const bf16x8*)(base + row * 512 + ((c8 ^ (row & 31)) << 3));
}

__device__ __forceinline__ float sigm(float v) { return 1.f / (1.f + expf(-v)); }

// ---------------------------------------------------------------------------
// Kernel 0: prep = Wg/Wf transpose -> bf16 FRAGMENT-MAJOR (pk), + qk tables.
// pk layout (R7-verified): entry [cblk=n>>5][ks32=k>>4][lane=(n&31)+32*((k>>3)&1)][k&7]
// blocks 0..511: col n of Wg/Wf. blocks 512..527: Q/K.
// ---------------------------------------------------------------------------
__global__ __launch_bounds__(512) void prep_kernel(
    const float* __restrict__ Wg, const float* __restrict__ Wf,
    __hip_bfloat16* __restrict__ WgPk, __hip_bfloat16* __restrict__ WfPk,
    const float* __restrict__ ve,
    const float* __restrict__ Wq, const float* __restrict__ bq,
    const float* __restrict__ Wk, const float* __restrict__ bk,
    float* __restrict__ Qm, float* __restrict__ Km)
{
    const int bx = blockIdx.x;
    if (bx < 512) {
        const int n = bx;
        const int k = threadIdx.x;
        const int cblk = n >> 5;
        const int ks32 = k >> 4;
        const int l    = (n & 31) + 32 * ((k >> 3) & 1);
        const size_t pkidx = (((size_t)cblk * 32 + ks32) * 64 + l) * 8 + (k & 7);
        WgPk[pkidx] = __float2bfloat16(Wg[(size_t)k * N_ + n]);
        WfPk[pkidx] = __float2bfloat16(Wf[(size_t)k * N_ + n]);
    } else {
        const int g = (bx - 512) * 512 + threadIdx.x;   // 0..8191
        const int j = g >> 4, h = g & 15;
        const float* vr = ve + j * H_;
        float q = bq[h], k = bk[h];
        #pragma unroll
        for (int m = 0; m < H_; ++m) {
            const float v = vr[m];
            q += v * Wq[m * H_ + h];
            k += v * Wk[m * H_ + h];
        }
        Qm[g] = q;
        Km[g] = k;
    }
}

// ---------------------------------------------------------------------------
// Kernel 1: top-8 neighbors. One wave per row n; shuffle-only selection.
// ---------------------------------------------------------------------------
__global__ __launch_bounds__(64) void topk_kernel(
    const float* __restrict__ Qm, const float* __restrict__ Km,
    float* __restrict__ w_out, int* __restrict__ idx_out)
{
    const int n = blockIdx.x;
    const int lane = threadIdx.x;

    float4 q0, q1, q2, q3;
    {
        const float4* qr = (const float4*)(Qm + n * H_);
        q0 = qr[0]; q1 = qr[1]; q2 = qr[2]; q3 = qr[3];
    }

    float sv[8]; int si[8];
    #pragma unroll
    for (int c = 0; c < 8; ++c) {
        const int j = c * 64 + lane;
        const float4* kr = (const float4*)(Km + j * H_);
        float4 k0 = kr[0], k1 = kr[1], k2 = kr[2], k3 = kr[3];
        float s = q0.x * k0.x + q0.y * k0.y + q0.z * k0.z + q0.w * k0.w
                + q1.x * k1.x + q1.y * k1.y + q1.z * k1.z + q1.w * k1.w
                + q2.x * k2.x + q2.y * k2.y + q2.z * k2.z + q2.w * k2.w
                + q3.x * k3.x + q3.y * k3.y + q3.z * k3.z + q3.w * k3.w;
        sv[c] = (j == n) ? -1e9f : s;
        si[c] = j;
    }

    float keepv[TOPK_]; int keepi[TOPK_];
    #pragma unroll
    for (int k = 0; k < TOPK_; ++k) {
        float bv = sv[0]; int bi = si[0]; int bslot = 0;
        #pragma unroll
        for (int c = 1; c < 8; ++c)
            if (sv[c] > bv || (sv[c] == bv && si[c] < bi)) { bv = sv[c]; bi = si[c]; bslot = c; }
        float v = bv; int i = bi;
        #pragma unroll
        for (int off = 32; off > 0; off >>= 1) {
            float v2 = __shfl_xor(v, off);
            int   i2 = __shfl_xor(i, off);
            if (v2 > v || (v2 == v && i2 < i)) { v = v2; i = i2; }
        }
        keepv[k] = v; keepi[k] = i;
        if (i == bi) sv[bslot] = -INFINITY;
    }

    if (lane == 0) {
        float vmax = keepv[0];
        float ev[TOPK_], esum = 0.f;
        #pragma unroll
        for (int k = 0; k < TOPK_; k++) { ev[k] = expf(keepv[k] - vmax); esum += ev[k]; }
        float inv = 1.f / esum;
        #pragma unroll
        for (int k = 0; k < TOPK_; k++) {
            w_out[n * TOPK_ + k] = ev[k] * inv;
            idx_out[n * TOPK_ + k] = keepi[k];
        }
    }
}

// ---------------------------------------------------------------------------
// Kernel 2: ring gather -> bf16 A matrix, fused with score s = x·Wscore+b.
// ---------------------------------------------------------------------------
__global__ __launch_bounds__(512) void ring_kernel(
    const float* __restrict__ x, const float* __restrict__ w,
    const int* __restrict__ idx,
    const float* __restrict__ Wscore, const float* __restrict__ bscore,
    __hip_bfloat16* __restrict__ ring, float* __restrict__ s)
{
    __shared__ float xs[RPB][N_];
    __shared__ float wsh[N_ * TOPK_];
    __shared__ int   ish[N_ * TOPK_];
    const int t = threadIdx.x;
    const int row0 = blockIdx.x * RPB;

    for (int i = t; i < N_ * TOPK_; i += 512) { wsh[i] = w[i]; ish[i] = idx[i]; }
    {
        const float4* xg = (const float4*)(x + (size_t)row0 * N_);
        float4* xsf = (float4*)&xs[0][0];
        xsf[t] = xg[t];
        xsf[t + 512] = xg[t + 512];
    }
    __syncthreads();

    {
        const int wv = t >> 6, lane = t & 63;
        float sa = 0.f;
        #pragma unroll
        for (int i = 0; i < 8; ++i) sa += xs[wv][lane + i * 64] * Wscore[lane + i * 64];
        for (int off = 32; off > 0; off >>= 1) sa += __shfl_down(sa, off);
        if (lane == 0) s[row0 + wv] = sa + bscore[0];
    }

    float wr[TOPK_]; int ir[TOPK_];
    #pragma unroll
    for (int k = 0; k < TOPK_; ++k) { wr[k] = wsh[t * TOPK_ + k]; ir[k] = ish[t * TOPK_ + k]; }
    #pragma unroll
    for (int r = 0; r < RPB; ++r) {
        float acc = 0.f;
        #pragma unroll
        for (int k = 0; k < TOPK_; ++k) acc += wr[k] * xs[r][ir[k]];
        ring[(size_t)(row0 + r) * N_ + t] = __float2bfloat16(acc);
    }
}

// ---------------------------------------------------------------------------
// Kernel 3: center_raw with inline softmax. grid B_*CRCH, 512 thr.
// ---------------------------------------------------------------------------
__global__ __launch_bounds__(512) void center_raw_kernel(
    const float* __restrict__ x, const float* __restrict__ s,
    float* __restrict__ craw_p)
{
    const int b = blockIdx.x >> 4;
    const int c = blockIdx.x & 15;
    const int n = threadIdx.x;
    __shared__ float red[8];
    __shared__ float ash[CRL];
    const float* srow = s + (size_t)b * L_;

    float lmax = -1e30f;
    for (int l = n; l < L_; l += 512) lmax = fmaxf(lmax, srow[l]);
    for (int off = 32; off > 0; off >>= 1) lmax = fmaxf(lmax, __shfl_down(lmax, off));
    if ((n & 63) == 0) red[n >> 6] = lmax;
    __syncthreads();
    float gmax = red[0];
    #pragma unroll
    for (int w = 1; w < 8; ++w) gmax = fmaxf(gmax, red[w]);
    __syncthreads();

    float lsum = 0.f;
    for (int l = n; l < L_; l += 512) lsum += expf(srow[l] - gmax);
    for (int off = 32; off > 0; off >>= 1) lsum += __shfl_down(lsum, off);
    if ((n & 63) == 0) red[n >> 6] = lsum;
    __syncthreads();
    float tsum = 0.f;
    #pragma unroll
    for (int w = 0; w < 8; ++w) tsum += red[w];
    const float inv = 1.f / tsum;

    const int l0 = c * CRL;
    if (n < CRL) ash[n] = expf(srow[l0 + n] - gmax) * inv;
    __syncthreads();

    const float* xb = x + ((size_t)b * L_ + l0) * N_;
    float acc = 0.f;
    #pragma unroll 3
    for (int l = 0; l < CRL; l++) acc += ash[l] * xb[(size_t)l * N_ + n];
    craw_p[(size_t)(b * CRCH + c) * N_ + n] = acc;
}

__device__ __forceinline__ float gelu_exact(float v) {
    return 0.5f * v * (1.0f + erff(v * 0.70710678118654752440f));
}

// ---------------------------------------------------------------------------
// Kernel 4: reduce partials + center MLP -> center. grid B_, 512 thr.
// ---------------------------------------------------------------------------
__global__ __launch_bounds__(512) void center_mlp_kernel(
    const float* __restrict__ craw_p,
    const float* __restrict__ Wc1, const float* __restrict__ bc1,
    const float* __restrict__ Wc2, const float* __restrict__ bc2,
    const float* __restrict__ Wcn, const float* __restrict__ bcn,
    float* __restrict__ center)
{
    const int b = blockIdx.x;
    const int t = threadIdx.x;
    const int col = t & 63;
    const int seg = t >> 6;
    __shared__ float cr[N_];
    __shared__ float psum[8][D_];
    __shared__ float h1[D_];
    __shared__ float h2[D_];

    {
        float acc = 0.f;
        #pragma unroll
        for (int c = 0; c < CRCH; ++c) acc += craw_p[(size_t)(b * CRCH + c) * N_ + t];
        cr[t] = acc;
    }
    __syncthreads();
    {
        float p = 0.f;
        #pragma unroll 8
        for (int m = seg * 64; m < seg * 64 + 64; ++m) p += cr[m] * Wc1[m * D_ + col];
        psum[seg][col] = p;
    }
    __syncthreads();
    if (t < D_) {
        float acc = bc1[t];
        #pragma unroll
        for (int s2 = 0; s2 < 8; ++s2) acc += psum[s2][t];
        h1[t] = gelu_exact(acc);
    }
    __syncthreads();
    if (t < D_) {
        float acc = bc2[t];
        #pragma unroll 8
        for (int j = 0; j < D_; j++) acc += h1[j] * Wc2[j * D_ + t];
        h2[t] = gelu_exact(acc);
    }
    __syncthreads();
    {
        float acc = bcn[t];
        #pragma unroll 8
        for (int j = 0; j < D_; j++) acc += h2[j] * Wcn[j * N_ + t];
        center[b * N_ + t] = acc;
    }
}

// ---------------------------------------------------------------------------
// Kernel 5: cg[b,n] = center[b]·Wg[512+.,n] + bg[n]. (parallel form)
// ---------------------------------------------------------------------------
__global__ __launch_bounds__(512) void cg_kernel(
    const float* __restrict__ center, const float* __restrict__ Wg,
    const float* __restrict__ bg, float* __restrict__ cg)
{
    const int nc = blockIdx.x;
    const int b  = blockIdx.y;
    const int t  = threadIdx.x;
    const int col = nc * 64 + (t & 63);
    const int seg = t >> 6;
    __shared__ float cs[N_];
    __shared__ float psum[8][64];

    cs[t] = center[b * N_ + t];
    __syncthreads();
    {
        float p = 0.f;
        const float* wp = Wg + (size_t)(N_ + seg * 64) * N_ + col;
        #pragma unroll 8
        for (int m = 0; m < 64; ++m) { p += cs[seg * 64 + m] * wp[0]; wp += N_; }
        psum[seg][t & 63] = p;
    }
    __syncthreads();
    if (t < 64) {
        float acc = bg[nc * 64 + t];
        #pragma unroll
        for (int s2 = 0; s2 < 8; ++s2) acc += psum[s2][t];
        cg[b * N_ + nc * 64 + t] = acc;
    }
}

// ---------------------------------------------------------------------------
// Kernel 6: fused tail v4 -- gate GEMM + sigmoid mix + out GEMM + LN.
// R8 geometry (PROWS=32, 512 thr, grid 720 -- best measured) with:
//  * depth-1 register prefetch of W fragments in both GEMM loops (the R8
//    counters showed VGPR=44 -> compiler kept no W loads in flight; each
//    iteration exposed a full L2 round trip against ~30cyc of compute)
//  * cg/center read direct from global in the epilogue (drops 8KB LDS
//    staging; tables are L2-resident)
// VGPR must stay <= 64 (m69 occupancy cliff; R9's 68 halved waves/SIMD).
// LDS ~34KB. fused stays in Rsh (in-place, swizzled) -- never touches HBM.
// ---------------------------------------------------------------------------
__global__ __launch_bounds__(512) void tail_kernel(
    const __hip_bfloat16* __restrict__ ring,
    const __hip_bfloat16* __restrict__ WgPk,
    const __hip_bfloat16* __restrict__ WfPk,
    const float* __restrict__ cg,
    const float* __restrict__ center,
    const float* __restrict__ x,
    const float* __restrict__ bfv,
    const float* __restrict__ gamma,
    const float* __restrict__ beta,
    float* __restrict__ out)
{
    __shared__ __attribute__((aligned(16))) __hip_bfloat16 Rsh[PROWS * N_]; // 32 KB
    __shared__ float ps[8][32];
    __shared__ float pq[8][32];

    const int tid  = threadIdx.x;
    const int lane = tid & 63;
    const int wv8  = tid >> 6;        // 0..7, owns cols [wv8*64, +64)
    const int m32  = lane & 31;
    const int half = lane >> 5;
    const int row0 = blockIdx.x * PROWS;
    const int b0   = row0 / L_;
    const int b1   = (row0 + PROWS - 1) / L_;
    const int rowg = row0 + m32;                   // this lane's sample row
    const int bb   = (rowg / L_ != b0) ? b1 : b0;  // this lane's batch

    // ---- stage full ring panel (pre-swizzled source, linear dest) ----
    #pragma unroll
    for (int r = 0; r < 4; ++r) {
        const int row = r * 8 + wv8;
        const int c8s = lane ^ (row & 31);
        async_cp16(ring + (size_t)(row0 + row) * N_ + c8s * 8,
                   Rsh + row * 512);
    }
    __syncthreads();   // drains vmcnt: panel ready

    // ---- gate GEMM: barrier-free, W direct frag-major, depth-1 prefetch ----
    f32x16 ga0 = fzero16(), ga1 = fzero16();
    {
        const __hip_bfloat16* wbase = WgPk + ((size_t)(wv8 * 2) * 32 * 64 + lane) * 8;
        bf16x8 wa = *(const bf16x8*)(wbase);
        bf16x8 wb = *(const bf16x8*)(wbase + (size_t)32 * 64 * 8);
        #pragma unroll
        for (int ks32 = 0; ks32 < 32; ++ks32) {
            bf16x8 wan = wa, wbn = wb;
            if (ks32 < 31) {
                wan = *(const bf16x8*)(wbase + (size_t)(ks32 + 1) * 64 * 8);
                wbn = *(const bf16x8*)(wbase + (size_t)(32 * 64 + (ks32 + 1) * 64) * 8);
            }
            const int c8 = ks32 * 2 + half;
            bf16x8 d0 = rsh_ld(Rsh, m32, c8);
            ga0 = __builtin_amdgcn_mfma_f32_32x32x16_bf16(wa, d0, ga0, 0, 0, 0);
            ga1 = __builtin_amdgcn_mfma_f32_32x32x16_bf16(wb, d0, ga1, 0, 0, 0);
            wa = wan; wb = wbn;
        }
    }
    __syncthreads();   // all Rsh reads complete before in-place overwrite

    // ---- gate epilogue: sigmoid mix -> fused, in place in Rsh ----
#define GEPI(AC, I)                                                            \
    {                                                                          \
        const int ntb = (wv8 * 2 + (I)) * 32;                                  \
        _Pragma("unroll") for (int q = 0; q < 4; ++q) {                        \
            const int nb = ntb + 8 * q + 4 * half;                             \
            const float4 cgq = *(const float4*)(cg + (size_t)bb * N_ + nb);    \
            const float4 ctq = *(const float4*)(center + (size_t)bb * N_ + nb);\
            __hip_bfloat16* slot = Rsh + m32 * 512 +                           \
                                   (((nb >> 3) ^ m32) << 3) + (nb & 7);        \
            const uint2 rvp = *(const uint2*)slot;                             \
            const float rv0 = __uint_as_float((rvp.x & 0xffffu) << 16);        \
            const float rv1 = __uint_as_float((rvp.x >> 16) << 16);            \
            const float rv2 = __uint_as_float((rvp.y & 0xffffu) << 16);        \
            const float rv3 = __uint_as_float((rvp.y >> 16) << 16);            \
            const float g0 = sigm(AC[4 * q + 0] + cgq.x);                      \
            const float g1 = sigm(AC[4 * q + 1] + cgq.y);                      \
            const float g2 = sigm(AC[4 * q + 2] + cgq.z);                      \
            const float g3 = sigm(AC[4 * q + 3] + cgq.w);                      \
            const float f0 = g0 * rv0 + (1.f - g0) * ctq.x;                    \
            const float f1 = g1 * rv1 + (1.f - g1) * ctq.y;                    \
            const float f2 = g2 * rv2 + (1.f - g2) * ctq.z;                    \
            const float f3 = g3 * rv3 + (1.f - g3) * ctq.w;                    \
            uint2 wpk;                                                         \
            wpk.x = (unsigned)__builtin_bit_cast(unsigned short, __float2bfloat16(f0)) |        \
                    ((unsigned)__builtin_bit_cast(unsigned short, __float2bfloat16(f1)) << 16); \
            wpk.y = (unsigned)__builtin_bit_cast(unsigned short, __float2bfloat16(f2)) |        \
                    ((unsigned)__builtin_bit_cast(unsigned short, __float2bfloat16(f3)) << 16); \
            *(uint2*)slot = wpk;                                               \
        }                                                                      \
    }
    GEPI(ga0, 0) GEPI(ga1, 1)
    __syncthreads();   // fused panel complete

    // ---- out GEMM: barrier-free, W direct frag-major, depth-1 prefetch ----
    f32x16 oc0 = fzero16(), oc1 = fzero16();
    {
        const __hip_bfloat16* wbase = WfPk + ((size_t)(wv8 * 2) * 32 * 64 + lane) * 8;
        bf16x8 wa = *(const bf16x8*)(wbase);
        bf16x8 wb = *(const bf16x8*)(wbase + (size_t)32 * 64 * 8);
        #pragma unroll
        for (int ks32 = 0; ks32 < 32; ++ks32) {
            bf16x8 wan = wa, wbn = wb;
            if (ks32 < 31) {
                wan = *(const bf16x8*)(wbase + (size_t)(ks32 + 1) * 64 * 8);
                wbn = *(const bf16x8*)(wbase + (size_t)(32 * 64 + (ks32 + 1) * 64) * 8);
            }
            const int c8 = ks32 * 2 + half;
            bf16x8 d0 = rsh_ld(Rsh, m32, c8);
            oc0 = __builtin_amdgcn_mfma_f32_32x32x16_bf16(wa, d0, oc0, 0, 0, 0);
            oc1 = __builtin_amdgcn_mfma_f32_32x32x16_bf16(wb, d0, oc1, 0, 0, 0);
            wa = wan; wb = wbn;
        }
    }

    // ---- out epilogue: h = acc + bf + x; accumulate LN stats ----
    float ls = 0.f, lq = 0.f;
#define OEPI2(AC, I)                                                           \
    {                                                                          \
        const int ntb = (wv8 * 2 + (I)) * 32;                                  \
        _Pragma("unroll") for (int q = 0; q < 4; ++q) {                        \
            const int nb = ntb + 8 * q + 4 * half;                             \
            const float4 bq = *(const float4*)(bfv + nb);                      \
            const float4 xq = *(const float4*)(x + (size_t)rowg * N_ + nb);    \
            AC[4 * q + 0] += bq.x + xq.x;                                      \
            AC[4 * q + 1] += bq.y + xq.y;                                      \
            AC[4 * q + 2] += bq.z + xq.z;                                      \
            AC[4 * q + 3] += bq.w + xq.w;                                      \
            ls += AC[4 * q + 0] + AC[4 * q + 1] + AC[4 * q + 2] + AC[4 * q + 3]; \
            lq += AC[4 * q + 0] * AC[4 * q + 0] + AC[4 * q + 1] * AC[4 * q + 1]  \
                + AC[4 * q + 2] * AC[4 * q + 2] + AC[4 * q + 3] * AC[4 * q + 3]; \
        }                                                                      \
    }
    OEPI2(oc0, 0) OEPI2(oc1, 1)

    // ---- LN reduce: halves via shuffle, waves via LDS ----
    ls += __shfl_xor(ls, 32);
    lq += __shfl_xor(lq, 32);
    if (half == 0) { ps[wv8][m32] = ls; pq[wv8][m32] = lq; }
    __syncthreads();

    float S = 0.f, Q2 = 0.f;
    #pragma unroll
    for (int w = 0; w < 8; ++w) { S += ps[w][m32]; Q2 += pq[w][m32]; }
    const float mu  = S * (1.0f / N_);
    const float var = Q2 * (1.0f / N_) - mu * mu;
    const float inv = rsqrtf(var + 1e-5f);

#define LSTORE2(AC, I)                                                         \
    {                                                                          \
        const int ntb = (wv8 * 2 + (I)) * 32;                                  \
        _Pragma("unroll") for (int q = 0; q < 4; ++q) {                        \
            const int nb = ntb + 8 * q + 4 * half;                             \
            const float4 g4 = *(const float4*)(gamma + nb);                    \
            const float4 b4 = *(const float4*)(beta + nb);                     \
            float4 o;                                                          \
            o.x = (AC[4 * q + 0] - mu) * inv * g4.x + b4.x;                    \
            o.y = (AC[4 * q + 1] - mu) * inv * g4.y + b4.y;                    \
            o.z = (AC[4 * q + 2] - mu) * inv * g4.z + b4.z;                    \
            o.w = (AC[4 * q + 3] - mu) * inv * g4.w + b4.w;                    \
            *(float4*)(out + (size_t)rowg * N_ + nb) = o;                      \
        }                                                                      \
    }
    LSTORE2(oc0, 0) LSTORE2(oc1, 1)
}

// ---------------------------------------------------------------------------
extern "C" void kernel_launch(void* const* d_in, const int* in_sizes, int n_in,
                              void* d_out, int out_size, void* d_ws, size_t ws_size,
                              hipStream_t stream) {
    const float* x       = (const float*)d_in[0];
    const float* ve      = (const float*)d_in[1];
    const float* Wq      = (const float*)d_in[2];
    const float* bq      = (const float*)d_in[3];
    const float* Wk      = (const float*)d_in[4];
    const float* bk      = (const float*)d_in[5];
    const float* Wscore  = (const float*)d_in[6];
    const float* bscore  = (const float*)d_in[7];
    const float* Wc1     = (const float*)d_in[8];
    const float* bc1     = (const float*)d_in[9];
    const float* Wc2     = (const float*)d_in[10];
    const float* bc2     = (const float*)d_in[11];
    const float* Wcn     = (const float*)d_in[12];
    const float* bcn     = (const float*)d_in[13];
    const float* Wg      = (const float*)d_in[14];
    const float* bg      = (const float*)d_in[15];
    const float* Wf      = (const float*)d_in[16];
    const float* bf      = (const float*)d_in[17];
    const float* gamma   = (const float*)d_in[18];
    const float* beta    = (const float*)d_in[19];
    float* out = (float*)d_out;

    char* p = (char*)d_ws;
    float* ws_w    = (float*)p; p += N_ * TOPK_ * sizeof(float);
    int*   ws_idx  = (int*)p;   p += N_ * TOPK_ * sizeof(int);
    float* ws_s    = (float*)p; p += B_ * L_ * sizeof(float);
    float* ws_crp  = (float*)p; p += B_ * CRCH * N_ * sizeof(float);
    float* ws_cent = (float*)p; p += B_ * N_ * sizeof(float);
    float* ws_cg   = (float*)p; p += B_ * N_ * sizeof(float);
    float* ws_Q    = (float*)p; p += N_ * H_ * sizeof(float);
    float* ws_K    = (float*)p; p += N_ * H_ * sizeof(float);
    __hip_bfloat16* ws_ring  = (__hip_bfloat16*)p; p += (size_t)M_ * N_ * sizeof(__hip_bfloat16);
    __hip_bfloat16* ws_WgPk  = (__hip_bfloat16*)p; p += (size_t)N_ * N_ * sizeof(__hip_bfloat16);
    __hip_bfloat16* ws_WfPk  = (__hip_bfloat16*)p; p += (size_t)N_ * N_ * sizeof(__hip_bfloat16);

    prep_kernel<<<528, 512, 0, stream>>>(Wg, Wf, ws_WgPk, ws_WfPk,
                                         ve, Wq, bq, Wk, bk, ws_Q, ws_K);
    topk_kernel<<<N_, 64, 0, stream>>>(ws_Q, ws_K, ws_w, ws_idx);
    ring_kernel<<<M_ / RPB, 512, 0, stream>>>(x, ws_w, ws_idx, Wscore, bscore,
                                              ws_ring, ws_s);
    center_raw_kernel<<<B_ * CRCH, 512, 0, stream>>>(x, ws_s, ws_crp);
    center_mlp_kernel<<<B_, 512, 0, stream>>>(ws_crp, Wc1, bc1, Wc2, bc2,
                                              Wcn, bcn, ws_cent);
    cg_kernel<<<dim3(8, B_), 512, 0, stream>>>(ws_cent, Wg, bg, ws_cg);
    tail_kernel<<<M_ / PROWS, 512, 0, stream>>>(ws_ring, ws_WgPk, ws_WfPk,
                                                ws_cg, ws_cent, x, bf,
                                                gamma, beta, out);
}

// Round 11
// 240.313 us; speedup vs baseline: 1.1148x; 1.0407x over previous
//
#include <hip/hip_runtime.h>
#include <hip/hip_bf16.h>
#include <math.h>

#define B_ 32
#define L_ 720
#define N_ 512
#define H_ 16
#define D_ 64
#define TOPK_ 8
#define M_ (B_ * L_)          // 23040 rows
#define RPB 8                 // rows per ring block
#define CRCH 16               // center_raw chunks per batch
#define CRL (L_ / CRCH)       // 45
#define PROWS 32              // rows per tail panel

typedef __bf16 bf16x8 __attribute__((ext_vector_type(8)));
typedef float f32x16 __attribute__((ext_vector_type(16)));

// ---------------------------------------------------------------------------
// async 16B global -> LDS (dest = wave-uniform lds base + lane*16)
// ---------------------------------------------------------------------------
__device__ __forceinline__ void async_cp16(const __hip_bfloat16* g, __hip_bfloat16* l) {
    __builtin_amdgcn_global_load_lds(
        (const __attribute__((address_space(1))) void*)g,
        (__attribute__((address_space(3))) void*)l, 16, 0, 0);
}

__device__ __forceinline__ f32x16 fzero16() {
    f32x16 z;
    #pragma unroll
    for (int e = 0; e < 16; ++e) z[e] = 0.f;
    return z;
}

// swizzled full-panel read: element (row, 8-group c8) at row*512 + (c8^(row&31))*8
__device__ __forceinline__ bf16x8 rsh_ld(const __hip_bfloat16* base, int row, int c8) {
    return *(const bf16x8*)(base + row * 512 + ((c8 ^ (row & 31)) << 3));
}

__device__ __forceinline__ float sigm(float v) { return 1.f / (1.f + expf(-v)); }

// ---------------------------------------------------------------------------
// Kernel 0: prep = Wg/Wf transpose -> bf16 FRAGMENT-MAJOR (pk), + qk tables.
// pk layout (R7-verified): entry [cblk=n>>5][ks32=k>>4][lane=(n&31)+32*((k>>3)&1)][k&7]
// blocks 0..511: col n of Wg/Wf. blocks 512..527: Q/K.
// ---------------------------------------------------------------------------
__global__ __launch_bounds__(512) void prep_kernel(
    const float* __restrict__ Wg, const float* __restrict__ Wf,
    __hip_bfloat16* __restrict__ WgPk, __hip_bfloat16* __restrict__ WfPk,
    const float* __restrict__ ve,
    const float* __restrict__ Wq, const float* __restrict__ bq,
    const float* __restrict__ Wk, const float* __restrict__ bk,
    float* __restrict__ Qm, float* __restrict__ Km)
{
    const int bx = blockIdx.x;
    if (bx < 512) {
        const int n = bx;
        const int k = threadIdx.x;
        const int cblk = n >> 5;
        const int ks32 = k >> 4;
        const int l    = (n & 31) + 32 * ((k >> 3) & 1);
        const size_t pkidx = (((size_t)cblk * 32 + ks32) * 64 + l) * 8 + (k & 7);
        WgPk[pkidx] = __float2bfloat16(Wg[(size_t)k * N_ + n]);
        WfPk[pkidx] = __float2bfloat16(Wf[(size_t)k * N_ + n]);
    } else {
        const int g = (bx - 512) * 512 + threadIdx.x;   // 0..8191
        const int j = g >> 4, h = g & 15;
        const float* vr = ve + j * H_;
        float q = bq[h], k = bk[h];
        #pragma unroll
        for (int m = 0; m < H_; ++m) {
            const float v = vr[m];
            q += v * Wq[m * H_ + h];
            k += v * Wk[m * H_ + h];
        }
        Qm[g] = q;
        Km[g] = k;
    }
}

// ---------------------------------------------------------------------------
// Kernel 1: top-8 neighbors. One wave per row n; shuffle-only selection.
// ---------------------------------------------------------------------------
__global__ __launch_bounds__(64) void topk_kernel(
    const float* __restrict__ Qm, const float* __restrict__ Km,
    float* __restrict__ w_out, int* __restrict__ idx_out)
{
    const int n = blockIdx.x;
    const int lane = threadIdx.x;

    float4 q0, q1, q2, q3;
    {
        const float4* qr = (const float4*)(Qm + n * H_);
        q0 = qr[0]; q1 = qr[1]; q2 = qr[2]; q3 = qr[3];
    }

    float sv[8]; int si[8];
    #pragma unroll
    for (int c = 0; c < 8; ++c) {
        const int j = c * 64 + lane;
        const float4* kr = (const float4*)(Km + j * H_);
        float4 k0 = kr[0], k1 = kr[1], k2 = kr[2], k3 = kr[3];
        float s = q0.x * k0.x + q0.y * k0.y + q0.z * k0.z + q0.w * k0.w
                + q1.x * k1.x + q1.y * k1.y + q1.z * k1.z + q1.w * k1.w
                + q2.x * k2.x + q2.y * k2.y + q2.z * k2.z + q2.w * k2.w
                + q3.x * k3.x + q3.y * k3.y + q3.z * k3.z + q3.w * k3.w;
        sv[c] = (j == n) ? -1e9f : s;
        si[c] = j;
    }

    float keepv[TOPK_]; int keepi[TOPK_];
    #pragma unroll
    for (int k = 0; k < TOPK_; ++k) {
        float bv = sv[0]; int bi = si[0]; int bslot = 0;
        #pragma unroll
        for (int c = 1; c < 8; ++c)
            if (sv[c] > bv || (sv[c] == bv && si[c] < bi)) { bv = sv[c]; bi = si[c]; bslot = c; }
        float v = bv; int i = bi;
        #pragma unroll
        for (int off = 32; off > 0; off >>= 1) {
            float v2 = __shfl_xor(v, off);
            int   i2 = __shfl_xor(i, off);
            if (v2 > v || (v2 == v && i2 < i)) { v = v2; i = i2; }
        }
        keepv[k] = v; keepi[k] = i;
        if (i == bi) sv[bslot] = -INFINITY;
    }

    if (lane == 0) {
        float vmax = keepv[0];
        float ev[TOPK_], esum = 0.f;
        #pragma unroll
        for (int k = 0; k < TOPK_; k++) { ev[k] = expf(keepv[k] - vmax); esum += ev[k]; }
        float inv = 1.f / esum;
        #pragma unroll
        for (int k = 0; k < TOPK_; k++) {
            w_out[n * TOPK_ + k] = ev[k] * inv;
            idx_out[n * TOPK_ + k] = keepi[k];
        }
    }
}

// ---------------------------------------------------------------------------
// Kernel 2: ring gather -> bf16 A matrix, fused with score s = x·Wscore+b.
// v2: w/idx read DIRECTLY per thread (64B, L2-resident, aligned) instead of
// staging the full 16KB table per block (2880 blocks x 16KB = 46MB L2 reads
// removed, plus a staging loop and 20KB LDS).
// ---------------------------------------------------------------------------
__global__ __launch_bounds__(512) void ring_kernel(
    const float* __restrict__ x, const float* __restrict__ w,
    const int* __restrict__ idx,
    const float* __restrict__ Wscore, const float* __restrict__ bscore,
    __hip_bfloat16* __restrict__ ring, float* __restrict__ s)
{
    __shared__ float xs[RPB][N_];
    const int t = threadIdx.x;
    const int row0 = blockIdx.x * RPB;

    // per-thread top-k table (this thread's output column t)
    const float4* wp = (const float4*)(w + t * TOPK_);
    const int4*   ip = (const int4*)(idx + t * TOPK_);
    const float4 w0 = wp[0], w1 = wp[1];
    const int4   i0 = ip[0], i1 = ip[1];

    {
        const float4* xg = (const float4*)(x + (size_t)row0 * N_);
        float4* xsf = (float4*)&xs[0][0];
        xsf[t] = xg[t];
        xsf[t + 512] = xg[t + 512];
    }
    __syncthreads();

    {
        const int wv = t >> 6, lane = t & 63;
        float sa = 0.f;
        #pragma unroll
        for (int i = 0; i < 8; ++i) sa += xs[wv][lane + i * 64] * Wscore[lane + i * 64];
        for (int off = 32; off > 0; off >>= 1) sa += __shfl_down(sa, off);
        if (lane == 0) s[row0 + wv] = sa + bscore[0];
    }

    #pragma unroll
    for (int r = 0; r < RPB; ++r) {
        float acc = w0.x * xs[r][i0.x] + w0.y * xs[r][i0.y]
                  + w0.z * xs[r][i0.z] + w0.w * xs[r][i0.w]
                  + w1.x * xs[r][i1.x] + w1.y * xs[r][i1.y]
                  + w1.z * xs[r][i1.z] + w1.w * xs[r][i1.w];
        ring[(size_t)(row0 + r) * N_ + t] = __float2bfloat16(acc);
    }
}

// ---------------------------------------------------------------------------
// Kernel 3: center_raw with inline softmax. grid B_*CRCH, 512 thr.
// ---------------------------------------------------------------------------
__global__ __launch_bounds__(512) void center_raw_kernel(
    const float* __restrict__ x, const float* __restrict__ s,
    float* __restrict__ craw_p)
{
    const int b = blockIdx.x >> 4;
    const int c = blockIdx.x & 15;
    const int n = threadIdx.x;
    __shared__ float red[8];
    __shared__ float ash[CRL];
    const float* srow = s + (size_t)b * L_;

    float lmax = -1e30f;
    for (int l = n; l < L_; l += 512) lmax = fmaxf(lmax, srow[l]);
    for (int off = 32; off > 0; off >>= 1) lmax = fmaxf(lmax, __shfl_down(lmax, off));
    if ((n & 63) == 0) red[n >> 6] = lmax;
    __syncthreads();
    float gmax = red[0];
    #pragma unroll
    for (int w = 1; w < 8; ++w) gmax = fmaxf(gmax, red[w]);
    __syncthreads();

    float lsum = 0.f;
    for (int l = n; l < L_; l += 512) lsum += expf(srow[l] - gmax);
    for (int off = 32; off > 0; off >>= 1) lsum += __shfl_down(lsum, off);
    if ((n & 63) == 0) red[n >> 6] = lsum;
    __syncthreads();
    float tsum = 0.f;
    #pragma unroll
    for (int w = 0; w < 8; ++w) tsum += red[w];
    const float inv = 1.f / tsum;

    const int l0 = c * CRL;
    if (n < CRL) ash[n] = expf(srow[l0 + n] - gmax) * inv;
    __syncthreads();

    const float* xb = x + ((size_t)b * L_ + l0) * N_;
    float acc = 0.f;
    #pragma unroll 3
    for (int l = 0; l < CRL; l++) acc += ash[l] * xb[(size_t)l * N_ + n];
    craw_p[(size_t)(b * CRCH + c) * N_ + n] = acc;
}

__device__ __forceinline__ float gelu_exact(float v) {
    return 0.5f * v * (1.0f + erff(v * 0.70710678118654752440f));
}

// ---------------------------------------------------------------------------
// Kernel 4: reduce partials + center MLP -> center. grid B_, 512 thr.
// ---------------------------------------------------------------------------
__global__ __launch_bounds__(512) void center_mlp_kernel(
    const float* __restrict__ craw_p,
    const float* __restrict__ Wc1, const float* __restrict__ bc1,
    const float* __restrict__ Wc2, const float* __restrict__ bc2,
    const float* __restrict__ Wcn, const float* __restrict__ bcn,
    float* __restrict__ center)
{
    const int b = blockIdx.x;
    const int t = threadIdx.x;
    const int col = t & 63;
    const int seg = t >> 6;
    __shared__ float cr[N_];
    __shared__ float psum[8][D_];
    __shared__ float h1[D_];
    __shared__ float h2[D_];

    {
        float acc = 0.f;
        #pragma unroll
        for (int c = 0; c < CRCH; ++c) acc += craw_p[(size_t)(b * CRCH + c) * N_ + t];
        cr[t] = acc;
    }
    __syncthreads();
    {
        float p = 0.f;
        #pragma unroll 8
        for (int m = seg * 64; m < seg * 64 + 64; ++m) p += cr[m] * Wc1[m * D_ + col];
        psum[seg][col] = p;
    }
    __syncthreads();
    if (t < D_) {
        float acc = bc1[t];
        #pragma unroll
        for (int s2 = 0; s2 < 8; ++s2) acc += psum[s2][t];
        h1[t] = gelu_exact(acc);
    }
    __syncthreads();
    if (t < D_) {
        float acc = bc2[t];
        #pragma unroll 8
        for (int j = 0; j < D_; j++) acc += h1[j] * Wc2[j * D_ + t];
        h2[t] = gelu_exact(acc);
    }
    __syncthreads();
    {
        float acc = bcn[t];
        #pragma unroll 8
        for (int j = 0; j < D_; j++) acc += h2[j] * Wcn[j * N_ + t];
        center[b * N_ + t] = acc;
    }
}

// ---------------------------------------------------------------------------
// Kernel 5: cg[b,n] = center[b]·Wg[512+.,n] + bg[n]. (parallel form)
// ---------------------------------------------------------------------------
__global__ __launch_bounds__(512) void cg_kernel(
    const float* __restrict__ center, const float* __restrict__ Wg,
    const float* __restrict__ bg, float* __restrict__ cg)
{
    const int nc = blockIdx.x;
    const int b  = blockIdx.y;
    const int t  = threadIdx.x;
    const int col = nc * 64 + (t & 63);
    const int seg = t >> 6;
    __shared__ float cs[N_];
    __shared__ float psum[8][64];

    cs[t] = center[b * N_ + t];
    __syncthreads();
    {
        float p = 0.f;
        const float* wp = Wg + (size_t)(N_ + seg * 64) * N_ + col;
        #pragma unroll 8
        for (int m = 0; m < 64; ++m) { p += cs[seg * 64 + m] * wp[0]; wp += N_; }
        psum[seg][t & 63] = p;
    }
    __syncthreads();
    if (t < 64) {
        float acc = bg[nc * 64 + t];
        #pragma unroll
        for (int s2 = 0; s2 < 8; ++s2) acc += psum[s2][t];
        cg[b * N_ + nc * 64 + t] = acc;
    }
}

// ---------------------------------------------------------------------------
// Kernel 6: fused tail v5 -- gate GEMM + sigmoid mix + out GEMM + LN.
// R10 structure (PROWS=32, 512 thr, depth-1 W prefetch, VGPR 60) plus:
//  * first W fragments issued BEFORE the post-stage barrier (free: barrier
//    drains vmcnt anyway, so W(0) is ready on entry)
//  * s_setprio(1) around both MFMA loops (T5: tail blocks are independent
//    and phase-staggered -- the attn-like regime where setprio measured +4-7%)
// VGPR must stay <= 64 (m69 occupancy cliff).
// ---------------------------------------------------------------------------
__global__ __launch_bounds__(512) void tail_kernel(
    const __hip_bfloat16* __restrict__ ring,
    const __hip_bfloat16* __restrict__ WgPk,
    const __hip_bfloat16* __restrict__ WfPk,
    const float* __restrict__ cg,
    const float* __restrict__ center,
    const float* __restrict__ x,
    const float* __restrict__ bfv,
    const float* __restrict__ gamma,
    const float* __restrict__ beta,
    float* __restrict__ out)
{
    __shared__ __attribute__((aligned(16))) __hip_bfloat16 Rsh[PROWS * N_]; // 32 KB
    __shared__ float ps[8][32];
    __shared__ float pq[8][32];

    const int tid  = threadIdx.x;
    const int lane = tid & 63;
    const int wv8  = tid >> 6;        // 0..7, owns cols [wv8*64, +64)
    const int m32  = lane & 31;
    const int half = lane >> 5;
    const int row0 = blockIdx.x * PROWS;
    const int b0   = row0 / L_;
    const int b1   = (row0 + PROWS - 1) / L_;
    const int rowg = row0 + m32;                   // this lane's sample row
    const int bb   = (rowg / L_ != b0) ? b1 : b0;  // this lane's batch

    // ---- stage full ring panel (pre-swizzled source, linear dest) ----
    #pragma unroll
    for (int r = 0; r < 4; ++r) {
        const int row = r * 8 + wv8;
        const int c8s = lane ^ (row & 31);
        async_cp16(ring + (size_t)(row0 + row) * N_ + c8s * 8,
                   Rsh + row * 512);
    }

    // issue gate W(0) before the barrier -- the barrier's vmcnt drain covers it
    const __hip_bfloat16* gwbase = WgPk + ((size_t)(wv8 * 2) * 32 * 64 + lane) * 8;
    bf16x8 gwa = *(const bf16x8*)(gwbase);
    bf16x8 gwb = *(const bf16x8*)(gwbase + (size_t)32 * 64 * 8);
    __syncthreads();   // drains vmcnt: panel + W(0) ready

    // ---- gate GEMM: barrier-free, W direct frag-major, depth-1 prefetch ----
    f32x16 ga0 = fzero16(), ga1 = fzero16();
    {
        bf16x8 wa = gwa, wb = gwb;
        __builtin_amdgcn_s_setprio(1);
        #pragma unroll
        for (int ks32 = 0; ks32 < 32; ++ks32) {
            bf16x8 wan = wa, wbn = wb;
            if (ks32 < 31) {
                wan = *(const bf16x8*)(gwbase + (size_t)(ks32 + 1) * 64 * 8);
                wbn = *(const bf16x8*)(gwbase + (size_t)(32 * 64 + (ks32 + 1) * 64) * 8);
            }
            const int c8 = ks32 * 2 + half;
            bf16x8 d0 = rsh_ld(Rsh, m32, c8);
            ga0 = __builtin_amdgcn_mfma_f32_32x32x16_bf16(wa, d0, ga0, 0, 0, 0);
            ga1 = __builtin_amdgcn_mfma_f32_32x32x16_bf16(wb, d0, ga1, 0, 0, 0);
            wa = wan; wb = wbn;
        }
        __builtin_amdgcn_s_setprio(0);
    }
    __syncthreads();   // all Rsh reads complete before in-place overwrite

    // ---- gate epilogue: sigmoid mix -> fused, in place in Rsh ----
#define GEPI(AC, I)                                                            \
    {                                                                          \
        const int ntb = (wv8 * 2 + (I)) * 32;                                  \
        _Pragma("unroll") for (int q = 0; q < 4; ++q) {                        \
            const int nb = ntb + 8 * q + 4 * half;                             \
            const float4 cgq = *(const float4*)(cg + (size_t)bb * N_ + nb);    \
            const float4 ctq = *(const float4*)(center + (size_t)bb * N_ + nb);\
            __hip_bfloat16* slot = Rsh + m32 * 512 +                           \
                                   (((nb >> 3) ^ m32) << 3) + (nb & 7);        \
            const uint2 rvp = *(const uint2*)slot;                             \
            const float rv0 = __uint_as_float((rvp.x & 0xffffu) << 16);        \
            const float rv1 = __uint_as_float((rvp.x >> 16) << 16);            \
            const float rv2 = __uint_as_float((rvp.y & 0xffffu) << 16);        \
            const float rv3 = __uint_as_float((rvp.y >> 16) << 16);            \
            const float g0 = sigm(AC[4 * q + 0] + cgq.x);                      \
            const float g1 = sigm(AC[4 * q + 1] + cgq.y);                      \
            const float g2 = sigm(AC[4 * q + 2] + cgq.z);                      \
            const float g3 = sigm(AC[4 * q + 3] + cgq.w);                      \
            const float f0 = g0 * rv0 + (1.f - g0) * ctq.x;                    \
            const float f1 = g1 * rv1 + (1.f - g1) * ctq.y;                    \
            const float f2 = g2 * rv2 + (1.f - g2) * ctq.z;                    \
            const float f3 = g3 * rv3 + (1.f - g3) * ctq.w;                    \
            uint2 wpk;                                                         \
            wpk.x = (unsigned)__builtin_bit_cast(unsigned short, __float2bfloat16(f0)) |        \
                    ((unsigned)__builtin_bit_cast(unsigned short, __float2bfloat16(f1)) << 16); \
            wpk.y = (unsigned)__builtin_bit_cast(unsigned short, __float2bfloat16(f2)) |        \
                    ((unsigned)__builtin_bit_cast(unsigned short, __float2bfloat16(f3)) << 16); \
            *(uint2*)slot = wpk;                                               \
        }                                                                      \
    }
    GEPI(ga0, 0) GEPI(ga1, 1)
    __syncthreads();   // fused panel complete

    // ---- out GEMM: barrier-free, W direct frag-major, depth-1 prefetch ----
    f32x16 oc0 = fzero16(), oc1 = fzero16();
    {
        const __hip_bfloat16* wbase = WfPk + ((size_t)(wv8 * 2) * 32 * 64 + lane) * 8;
        bf16x8 wa = *(const bf16x8*)(wbase);
        bf16x8 wb = *(const bf16x8*)(wbase + (size_t)32 * 64 * 8);
        __builtin_amdgcn_s_setprio(1);
        #pragma unroll
        for (int ks32 = 0; ks32 < 32; ++ks32) {
            bf16x8 wan = wa, wbn = wb;
            if (ks32 < 31) {
                wan = *(const bf16x8*)(wbase + (size_t)(ks32 + 1) * 64 * 8);
                wbn = *(const bf16x8*)(wbase + (size_t)(32 * 64 + (ks32 + 1) * 64) * 8);
            }
            const int c8 = ks32 * 2 + half;
            bf16x8 d0 = rsh_ld(Rsh, m32, c8);
            oc0 = __builtin_amdgcn_mfma_f32_32x32x16_bf16(wa, d0, oc0, 0, 0, 0);
            oc1 = __builtin_amdgcn_mfma_f32_32x32x16_bf16(wb, d0, oc1, 0, 0, 0);
            wa = wan; wb = wbn;
        }
        __builtin_amdgcn_s_setprio(0);
    }

    // ---- out epilogue: h = acc + bf + x; accumulate LN stats ----
    float ls = 0.f, lq = 0.f;
#define OEPI2(AC, I)                                                           \
    {                                                                          \
        const int ntb = (wv8 * 2 + (I)) * 32;                                  \
        _Pragma("unroll") for (int q = 0; q < 4; ++q) {                        \
            const int nb = ntb + 8 * q + 4 * half;                             \
            const float4 bq = *(const float4*)(bfv + nb);                      \
            const float4 xq = *(const float4*)(x + (size_t)rowg * N_ + nb);    \
            AC[4 * q + 0] += bq.x + xq.x;                                      \
            AC[4 * q + 1] += bq.y + xq.y;                                      \
            AC[4 * q + 2] += bq.z + xq.z;                                      \
            AC[4 * q + 3] += bq.w + xq.w;                                      \
            ls += AC[4 * q + 0] + AC[4 * q + 1] + AC[4 * q + 2] + AC[4 * q + 3]; \
            lq += AC[4 * q + 0] * AC[4 * q + 0] + AC[4 * q + 1] * AC[4 * q + 1]  \
                + AC[4 * q + 2] * AC[4 * q + 2] + AC[4 * q + 3] * AC[4 * q + 3]; \
        }                                                                      \
    }
    OEPI2(oc0, 0) OEPI2(oc1, 1)

    // ---- LN reduce: halves via shuffle, waves via LDS ----
    ls += __shfl_xor(ls, 32);
    lq += __shfl_xor(lq, 32);
    if (half == 0) { ps[wv8][m32] = ls; pq[wv8][m32] = lq; }
    __syncthreads();

    float S = 0.f, Q2 = 0.f;
    #pragma unroll
    for (int w = 0; w < 8; ++w) { S += ps[w][m32]; Q2 += pq[w][m32]; }
    const float mu  = S * (1.0f / N_);
    const float var = Q2 * (1.0f / N_) - mu * mu;
    const float inv = rsqrtf(var + 1e-5f);

#define LSTORE2(AC, I)                                                         \
    {                                                                          \
        const int ntb = (wv8 * 2 + (I)) * 32;                                  \
        _Pragma("unroll") for (int q = 0; q < 4; ++q) {                        \
            const int nb = ntb + 8 * q + 4 * half;                             \
            const float4 g4 = *(const float4*)(gamma + nb);                    \
            const float4 b4 = *(const float4*)(beta + nb);                     \
            float4 o;                                                          \
            o.x = (AC[4 * q + 0] - mu) * inv * g4.x + b4.x;                    \
            o.y = (AC[4 * q + 1] - mu) * inv * g4.y + b4.y;                    \
            o.z = (AC[4 * q + 2] - mu) * inv * g4.z + b4.z;                    \
            o.w = (AC[4 * q + 3] - mu) * inv * g4.w + b4.w;                    \
            *(float4*)(out + (size_t)rowg * N_ + nb) = o;                      \
        }                                                                      \
    }
    LSTORE2(oc0, 0) LSTORE2(oc1, 1)
}

// ---------------------------------------------------------------------------
extern "C" void kernel_launch(void* const* d_in, const int* in_sizes, int n_in,
                              void* d_out, int out_size, void* d_ws, size_t ws_size,
                              hipStream_t stream) {
    const float* x       = (const float*)d_in[0];
    const float* ve      = (const float*)d_in[1];
    const float* Wq      = (const float*)d_in[2];
    const float* bq      = (const float*)d_in[3];
    const float* Wk      = (const float*)d_in[4];
    const float* bk      = (const float*)d_in[5];
    const float* Wscore  = (const float*)d_in[6];
    const float* bscore  = (const float*)d_in[7];
    const float* Wc1     = (const float*)d_in[8];
    const float* bc1     = (const float*)d_in[9];
    const float* Wc2     = (const float*)d_in[10];
    const float* bc2     = (const float*)d_in[11];
    const float* Wcn     = (const float*)d_in[12];
    const float* bcn     = (const float*)d_in[13];
    const float* Wg      = (const float*)d_in[14];
    const float* bg      = (const float*)d_in[15];
    const float* Wf      = (const float*)d_in[16];
    const float* bf      = (const float*)d_in[17];
    const float* gamma   = (const float*)d_in[18];
    const float* beta    = (const float*)d_in[19];
    float* out = (float*)d_out;

    char* p = (char*)d_ws;
    float* ws_w    = (float*)p; p += N_ * TOPK_ * sizeof(float);
    int*   ws_idx  = (int*)p;   p += N_ * TOPK_ * sizeof(int);
    float* ws_s    = (float*)p; p += B_ * L_ * sizeof(float);
    float* ws_crp  = (float*)p; p += B_ * CRCH * N_ * sizeof(float);
    float* ws_cent = (float*)p; p += B_ * N_ * sizeof(float);
    float* ws_cg   = (float*)p; p += B_ * N_ * sizeof(float);
    float* ws_Q    = (float*)p; p += N_ * H_ * sizeof(float);
    float* ws_K    = (float*)p; p += N_ * H_ * sizeof(float);
    __hip_bfloat16* ws_ring  = (__hip_bfloat16*)p; p += (size_t)M_ * N_ * sizeof(__hip_bfloat16);
    __hip_bfloat16* ws_WgPk  = (__hip_bfloat16*)p; p += (size_t)N_ * N_ * sizeof(__hip_bfloat16);
    __hip_bfloat16* ws_WfPk  = (__hip_bfloat16*)p; p += (size_t)N_ * N_ * sizeof(__hip_bfloat16);

    prep_kernel<<<528, 512, 0, stream>>>(Wg, Wf, ws_WgPk, ws_WfPk,
                                         ve, Wq, bq, Wk, bk, ws_Q, ws_K);
    topk_kernel<<<N_, 64, 0, stream>>>(ws_Q, ws_K, ws_w, ws_idx);
    ring_kernel<<<M_ / RPB, 512, 0, stream>>>(x, ws_w, ws_idx, Wscore, bscore,
                                              ws_ring, ws_s);
    center_raw_kernel<<<B_ * CRCH, 512, 0, stream>>>(x, ws_s, ws_crp);
    center_mlp_kernel<<<B_, 512, 0, stream>>>(ws_crp, Wc1, bc1, Wc2, bc2,
                                              Wcn, bcn, ws_cent);
    cg_kernel<<<dim3(8, B_), 512, 0, stream>>>(ws_cent, Wg, bg, ws_cg);
    tail_kernel<<<M_ / PROWS, 512, 0, stream>>>(ws_ring, ws_WgPk, ws_WfPk,
                                                ws_cg, ws_cent, x, bf,
                                                gamma, beta, out);
}